// Round 7
// baseline (531.407 us; speedup 1.0000x reference)
//
#include <hip/hip_runtime.h>
#include <cstdint>
#include <cstddef>

#define NN 100000
#define NE 1600000
#define FD 128
#define NXCD 8
#define RNODES ((NN + NXCD - 1) / NXCD)   // 12500 nodes per XCD range

typedef int vi4 __attribute__((ext_vector_type(4)));

// ---- bf16 helpers (RNE), storage-only precision reduction ----
__device__ __forceinline__ float bf_lo(uint32_t u) { return __uint_as_float(u << 16); }
__device__ __forceinline__ float bf_hi(uint32_t u) { return __uint_as_float(u & 0xffff0000u); }
__device__ __forceinline__ uint32_t bf_pack(float a, float b) {
    uint32_t ua = __float_as_uint(a), ub = __float_as_uint(b);
    ua += 0x7fffu + ((ua >> 16) & 1u);
    ub += 0x7fffu + ((ub >> 16) & 1u);
    return (ua >> 16) | (ub & 0xffff0000u);
}

// ---------------- degree histogram, XCD-partitioned, nt streaming reads ----
__global__ __launch_bounds__(256) void k_hist(const int* __restrict__ dst,
                                              int* __restrict__ cnt, int e) {
    const int xcd   = blockIdx.x & 7;
    const int chunk = blockIdx.x >> 3;
    const int lo = xcd * RNODES;
    const int hi = lo + RNODES;
    const int base = chunk * 1024 + threadIdx.x * 4;
    if (base >= e) return;                 // e % 4 == 0
    vi4 d4 = __builtin_nontemporal_load((const vi4*)(dst + base));
    #pragma unroll
    for (int j = 0; j < 4; ++j) {
        int d = d4[j];
        if (d >= lo && d < hi) atomicAdd(&cnt[d], 1);
    }
}

// ---------------- exclusive scan (3 kernels) ----------------
__global__ __launch_bounds__(1024) void k_scan1(const int* __restrict__ cnt,
                                                int* __restrict__ excl,
                                                int* __restrict__ bsum, int n) {
    __shared__ int sh[1024];
    int i = blockIdx.x * 1024 + threadIdx.x;
    int v = (i < n) ? cnt[i] : 0;
    sh[threadIdx.x] = v;
    __syncthreads();
    for (int off = 1; off < 1024; off <<= 1) {
        int t = (threadIdx.x >= off) ? sh[threadIdx.x - off] : 0;
        __syncthreads();
        sh[threadIdx.x] += t;
        __syncthreads();
    }
    if (i < n) excl[i] = sh[threadIdx.x] - v;   // exclusive
    if (threadIdx.x == 1023) bsum[blockIdx.x] = sh[1023];
}

__global__ void k_scan2(int* __restrict__ bsum, int nb) {
    __shared__ int sh[128];
    int t = threadIdx.x;
    int v = (t < nb) ? bsum[t] : 0;
    sh[t] = v;
    __syncthreads();
    for (int off = 1; off < 128; off <<= 1) {
        int u = (t >= off) ? sh[t - off] : 0;
        __syncthreads();
        sh[t] += u;
        __syncthreads();
    }
    if (t < nb) bsum[t] = sh[t] - v;   // exclusive block offsets
}

// finalize row_ptr, init cursor, compute dis = rsqrt(deg+1)
__global__ void k_scan3(int* __restrict__ excl, const int* __restrict__ bsum,
                        int* __restrict__ cursor, const int* __restrict__ cnt,
                        float* __restrict__ dis, int n, int e) {
    int i = blockIdx.x * blockDim.x + threadIdx.x;
    if (i < n) {
        int v = excl[i] + bsum[i >> 10];
        excl[i] = v;
        cursor[i] = v;
        dis[i] = rsqrtf((float)(cnt[i] + 1));
    }
    if (i == 0) excl[n] = e;
}

// ---------------- CSR fill: paired {col,wedge} 8B store, nt streaming reads ---
__global__ __launch_bounds__(256) void k_fill(const int* __restrict__ src,
                                              const int* __restrict__ dst,
                                              int* __restrict__ cursor,
                                              uint2* __restrict__ colw,
                                              const float* __restrict__ dis, int e) {
    const int xcd   = blockIdx.x & 7;
    const int chunk = blockIdx.x >> 3;
    const int lo = xcd * RNODES;
    const int hi = lo + RNODES;
    const int base = chunk * 1024 + threadIdx.x * 4;
    if (base >= e) return;                 // e % 4 == 0
    vi4 d4 = __builtin_nontemporal_load((const vi4*)(dst + base));
    vi4 s4 = __builtin_nontemporal_load((const vi4*)(src + base));
    #pragma unroll
    for (int j = 0; j < 4; ++j) {
        int d = d4[j];
        if (d >= lo && d < hi) {
            int s   = s4[j];
            int pos = atomicAdd(&cursor[d], 1);
            uint2 cw;
            cw.x = (uint32_t)s;
            cw.y = __float_as_uint(dis[s] * dis[d]);
            colw[pos] = cw;                // single 8B store, L2-buffered
        }
    }
}

// ---------------- GEMM: H[n x 128] = X[n x 128] @ W[128 x 128] -> bf16 -------
template <typename TIN>
__global__ __launch_bounds__(256) void k_gemm(const TIN* __restrict__ X,
                                              const float* __restrict__ W,
                                              unsigned short* __restrict__ H, int n) {
    __shared__ float At[64][68];   // [k][row]
    __shared__ float Ws[64][64];   // [k][col]
    const int t  = threadIdx.x;
    const int tx = t & 15;
    const int ty = t >> 4;
    const int rb = blockIdx.x * 64;
    const int cb = blockIdx.y * 64;

    float acc[4][4] = {};

    for (int c = 0; c < 2; ++c) {
        #pragma unroll
        for (int r = 0; r < 4; ++r) {
            int f   = t + 256 * r;        // 0..1023
            int row = f >> 4;             // 0..63
            int kc  = (f & 15) << 2;      // 0..60 step 4
            int grow = rb + row;
            float4 v = make_float4(0.f, 0.f, 0.f, 0.f);
            if (grow < n) {
                if constexpr (sizeof(TIN) == 4) {
                    v = *(const float4*)((const float*)X + (size_t)grow * FD + c * 64 + kc);
                } else {
                    uint2 p = *(const uint2*)((const unsigned short*)X + (size_t)grow * FD + c * 64 + kc);
                    v.x = bf_lo(p.x); v.y = bf_hi(p.x);
                    v.z = bf_lo(p.y); v.w = bf_hi(p.y);
                }
            }
            At[kc + 0][row] = v.x;
            At[kc + 1][row] = v.y;
            At[kc + 2][row] = v.z;
            At[kc + 3][row] = v.w;
            *(float4*)&Ws[row][kc] =
                *(const float4*)(W + (size_t)(c * 64 + row) * FD + cb + kc);
        }
        __syncthreads();
        #pragma unroll 8
        for (int k = 0; k < 64; ++k) {
            float4 a = *(const float4*)&At[k][ty * 4];
            float4 b = *(const float4*)&Ws[k][tx * 4];
            acc[0][0] = fmaf(a.x, b.x, acc[0][0]);
            acc[0][1] = fmaf(a.x, b.y, acc[0][1]);
            acc[0][2] = fmaf(a.x, b.z, acc[0][2]);
            acc[0][3] = fmaf(a.x, b.w, acc[0][3]);
            acc[1][0] = fmaf(a.y, b.x, acc[1][0]);
            acc[1][1] = fmaf(a.y, b.y, acc[1][1]);
            acc[1][2] = fmaf(a.y, b.z, acc[1][2]);
            acc[1][3] = fmaf(a.y, b.w, acc[1][3]);
            acc[2][0] = fmaf(a.z, b.x, acc[2][0]);
            acc[2][1] = fmaf(a.z, b.y, acc[2][1]);
            acc[2][2] = fmaf(a.z, b.z, acc[2][2]);
            acc[2][3] = fmaf(a.z, b.w, acc[2][3]);
            acc[3][0] = fmaf(a.w, b.x, acc[3][0]);
            acc[3][1] = fmaf(a.w, b.y, acc[3][1]);
            acc[3][2] = fmaf(a.w, b.z, acc[3][2]);
            acc[3][3] = fmaf(a.w, b.w, acc[3][3]);
        }
        __syncthreads();
    }

    #pragma unroll
    for (int i = 0; i < 4; ++i) {
        int grow = rb + ty * 4 + i;
        if (grow < n) {
            uint2 p;
            p.x = bf_pack(acc[i][0], acc[i][1]);
            p.y = bf_pack(acc[i][2], acc[i][3]);
            *(uint2*)(H + (size_t)grow * FD + cb + tx * 4) = p;
        }
    }
}

// ---------------- 128-wide aggregation over bf16 rows --------------------
// TWO nodes per wave; per node ceil(deg/16) 16-deep gather groups.
// Full groups load metadata contiguously (wide scalar loads); boundary group
// uses clamped indices with zero weights. fp32 accumulation.
// MODE 0: writes relu rows (bf16). MODE 1: fused dot with W3 -> outf[i].
template <int MODE>
__global__ __launch_bounds__(256) void k_agg(const unsigned short* __restrict__ h,
                                             const float* __restrict__ dis,
                                             const int* __restrict__ rp,
                                             const uint2* __restrict__ colw,
                                             const float* __restrict__ bias,
                                             const float* __restrict__ W3,
                                             unsigned short* __restrict__ out,
                                             float* __restrict__ outf, int n) {
    const uint32_t* h32 = (const uint32_t*)h;   // 64 words per row
    int wid  = (int)((blockIdx.x * (size_t)blockDim.x + threadIdx.x) >> 6);
    int lane = threadIdx.x & 63;
    int w2 = __builtin_amdgcn_readfirstlane(wid);
    int i0 = 2 * w2;
    if (i0 >= n) return;
    int i1 = i0 + 1;
    const bool has1 = (i1 < n);

    const int e00 = rp[i0];
    const int e01 = rp[i0 + 1];
    const int e11 = has1 ? rp[i0 + 2] : e01;

    float di0 = dis[i0];
    float di1 = has1 ? dis[i1] : 0.f;
    float2 acc0, acc1;
    {
        uint32_t su0 = h32[(size_t)i0 * 64 + lane];
        float q0 = di0 * di0;
        acc0.x = bf_lo(su0) * q0; acc0.y = bf_hi(su0) * q0;
        if (has1) {
            uint32_t su1 = h32[(size_t)i1 * 64 + lane];
            float q1 = di1 * di1;
            acc1.x = bf_lo(su1) * q1; acc1.y = bf_hi(su1) * q1;
        } else { acc1.x = acc1.y = 0.f; }
    }

    const int ng0 = (e01 - e00 + 15) >> 4;
    const int ng1 = (e11 - e01 + 15) >> 4;
    const int ng  = ng0 > ng1 ? ng0 : ng1;

    for (int g = 0; g < ng; ++g) {
        const bool do0 = (g < ng0), do1 = (g < ng1);
        int s0[16], s1[16];
        float w0_[16], w1_[16];
        uint32_t v0[16], v1[16];
        if (do0) {
            const int jb = e00 + g * 16;
            if (jb + 16 <= e01) {
                #pragma unroll
                for (int q = 0; q < 16; ++q) {
                    uint2 cw = colw[jb + q];
                    s0[q] = (int)cw.x; w0_[q] = __uint_as_float(cw.y);
                }
            } else {
                #pragma unroll
                for (int q = 0; q < 16; ++q) {
                    int idx = jb + q;
                    int c   = idx < e01 ? idx : e01 - 1;
                    uint2 cw = colw[c];
                    s0[q]  = (int)cw.x;
                    w0_[q] = idx < e01 ? __uint_as_float(cw.y) : 0.f;
                }
            }
        }
        if (do1) {
            const int jb = e01 + g * 16;
            if (jb + 16 <= e11) {
                #pragma unroll
                for (int q = 0; q < 16; ++q) {
                    uint2 cw = colw[jb + q];
                    s1[q] = (int)cw.x; w1_[q] = __uint_as_float(cw.y);
                }
            } else {
                #pragma unroll
                for (int q = 0; q < 16; ++q) {
                    int idx = jb + q;
                    int c   = idx < e11 ? idx : e11 - 1;
                    uint2 cw = colw[c];
                    s1[q]  = (int)cw.x;
                    w1_[q] = idx < e11 ? __uint_as_float(cw.y) : 0.f;
                }
            }
        }
        if (do0) {
            #pragma unroll
            for (int q = 0; q < 16; ++q)
                v0[q] = h32[(size_t)s0[q] * 64 + lane];
        }
        if (do1) {
            #pragma unroll
            for (int q = 0; q < 16; ++q)
                v1[q] = h32[(size_t)s1[q] * 64 + lane];
        }
        if (do0) {
            #pragma unroll
            for (int q = 0; q < 16; ++q) {
                acc0.x = fmaf(w0_[q], bf_lo(v0[q]), acc0.x);
                acc0.y = fmaf(w0_[q], bf_hi(v0[q]), acc0.y);
            }
        }
        if (do1) {
            #pragma unroll
            for (int q = 0; q < 16; ++q) {
                acc1.x = fmaf(w1_[q], bf_lo(v1[q]), acc1.x);
                acc1.y = fmaf(w1_[q], bf_hi(v1[q]), acc1.y);
            }
        }
    }

    float2 b = ((const float2*)bias)[lane];
    acc0.x = fmaxf(acc0.x + b.x, 0.f);
    acc0.y = fmaxf(acc0.y + b.y, 0.f);
    acc1.x = fmaxf(acc1.x + b.x, 0.f);
    acc1.y = fmaxf(acc1.y + b.y, 0.f);

    if (MODE == 0) {
        ((uint32_t*)out)[(size_t)i0 * 64 + lane] = bf_pack(acc0.x, acc0.y);
        if (has1)
            ((uint32_t*)out)[(size_t)i1 * 64 + lane] = bf_pack(acc1.x, acc1.y);
    } else {
        float2 w3 = ((const float2*)W3)[lane];
        float d0 = acc0.x * w3.x + acc0.y * w3.y;
        float d1 = acc1.x * w3.x + acc1.y * w3.y;
        #pragma unroll
        for (int off = 32; off; off >>= 1) {
            d0 += __shfl_xor(d0, off);
            d1 += __shfl_xor(d1, off);
        }
        if (lane == 0) {
            outf[i0] = d0;
            if (has1) outf[i1] = d1;
        }
    }
}

// ---------------- scalar aggregation + bias + sigmoid (wave per node) ----------
__global__ __launch_bounds__(256) void k_agg1(const float* __restrict__ h3,
                                              const float* __restrict__ dis,
                                              const int* __restrict__ rp,
                                              const uint2* __restrict__ colw,
                                              const float* __restrict__ b3,
                                              float* __restrict__ out, int n) {
    int i    = (int)((blockIdx.x * (size_t)blockDim.x + threadIdx.x) >> 6);
    int lane = threadIdx.x & 63;
    if (i >= n) return;
    float di  = dis[i];
    float acc = (lane == 0) ? di * di * h3[i] : 0.f;
    const int e0 = rp[i], e1 = rp[i + 1];
    for (int base = e0 + lane; base < e1; base += 64) {
        uint2 cw = colw[base];
        acc = fmaf(__uint_as_float(cw.y), h3[(int)cw.x], acc);
    }
    #pragma unroll
    for (int off = 32; off; off >>= 1) acc += __shfl_xor(acc, off);
    if (lane == 0) {
        float v = acc + b3[0];
        out[i] = 1.f / (1.f + expf(-v));
    }
}

// ---------------- host launch ----------------
static inline size_t alg(size_t x) { return (x + 255) & ~(size_t)255; }

extern "C" void kernel_launch(void* const* d_in, const int* in_sizes, int n_in,
                              void* d_out, int out_size, void* d_ws, size_t ws_size,
                              hipStream_t stream) {
    const float* x   = (const float*)d_in[0];
    const int*   ei  = (const int*)d_in[1];     // [2, E]
    const float* W1  = (const float*)d_in[2];
    const float* b1  = (const float*)d_in[3];
    const float* W2  = (const float*)d_in[4];
    const float* b2  = (const float*)d_in[5];
    const float* W3  = (const float*)d_in[6];
    const float* b3  = (const float*)d_in[7];
    float*       out = (float*)d_out;

    const int n = NN, e = NE;
    const int* src = ei;
    const int* dst = ei + e;

    char* w = (char*)d_ws;
    float* dis    = (float*)w;  w += alg((size_t)n * 4);
    int*   cnt    = (int*)w;    w += alg((size_t)n * 4);
    int*   rp     = (int*)w;    w += alg((size_t)(n + 1) * 4);
    int*   cursor = (int*)w;    w += alg((size_t)n * 4);
    int*   bsum   = (int*)w;    w += alg((size_t)128 * 4);
    uint2* colw   = (uint2*)w;  w += alg((size_t)e * 8);
    unsigned short* bufA = (unsigned short*)w; w += alg((size_t)n * FD * 2);
    unsigned short* bufB = (unsigned short*)w; w += alg((size_t)n * FD * 2);
    float* h3     = (float*)w;  w += alg((size_t)n * 4);

    hipMemsetAsync(cnt, 0, (size_t)n * 4, stream);

    const int B = 256;
    const int gN = (n + B - 1) / B;
    const int nScan = (n + 1023) / 1024;   // 98
    const int nChunk = (e + 1023) / 1024;  // 1563

    k_hist<<<nChunk * NXCD, B, 0, stream>>>(dst, cnt, e);
    k_scan1<<<nScan, 1024, 0, stream>>>(cnt, rp, bsum, n);
    k_scan2<<<1, 128, 0, stream>>>(bsum, nScan);
    k_scan3<<<gN, B, 0, stream>>>(rp, bsum, cursor, cnt, dis, n, e);
    k_fill<<<nChunk * NXCD, B, 0, stream>>>(src, dst, cursor, colw, dis, e);

    dim3 gGemm((n + 63) / 64, 2);
    const int nWave2  = (n + 1) / 2;                    // two nodes per wave
    const int gWave2  = (nWave2 * 64 + B - 1) / B;      // blocks for k_agg
    const int gWave   = (n * 64 + B - 1) / B;           // wave per node (k_agg1)

    // layer 1
    k_gemm<float><<<gGemm, B, 0, stream>>>(x, W1, bufA, n);
    k_agg<0><<<gWave2, B, 0, stream>>>(bufA, dis, rp, colw, b1, W3, bufB, h3, n);
    // layer 2 (+ fused layer-3 matvec)
    k_gemm<unsigned short><<<gGemm, B, 0, stream>>>(bufB, W2, bufA, n);
    k_agg<1><<<gWave2, B, 0, stream>>>(bufA, dis, rp, colw, b2, W3, bufB, h3, n);
    // layer 3
    k_agg1<<<gWave, B, 0, stream>>>(h3, dis, rp, colw, b3, out, n);
}

// Round 9
// 525.111 us; speedup vs baseline: 1.0120x; 1.0120x over previous
//
#include <hip/hip_runtime.h>
#include <cstdint>
#include <cstddef>

#define NN 100000
#define NE 1600000
#define FD 128
#define NXCD 8
#define RNODES ((NN + NXCD - 1) / NXCD)   // 12500 nodes per XCD range
#define CAP 208192                        // per-bucket capacity (E/8 + 8k slack)

typedef int vi4 __attribute__((ext_vector_type(4)));

// ---- bf16 helpers (RNE), storage-only precision reduction ----
__device__ __forceinline__ float bf_lo(uint32_t u) { return __uint_as_float(u << 16); }
__device__ __forceinline__ float bf_hi(uint32_t u) { return __uint_as_float(u & 0xffff0000u); }
__device__ __forceinline__ uint32_t bf_pack(float a, float b) {
    uint32_t ua = __float_as_uint(a), ub = __float_as_uint(b);
    ua += 0x7fffu + ((ua >> 16) & 1u);
    ub += 0x7fffu + ((ub >> 16) & 1u);
    return (ua >> 16) | (ub & 0xffff0000u);
}

// ---------------- stage 1: bucket partition (each edge read ONCE) ----------
// bkt[b] gets packed u = (dlo<<17) | s  (dlo<12500 fits 14b, s<100000 fits 17b)
__global__ __launch_bounds__(256) void k_part(const int* __restrict__ src,
                                              const int* __restrict__ dst,
                                              uint32_t* __restrict__ bkt,
                                              int* __restrict__ bcnt, int e) {
    __shared__ int scnt[8];
    __shared__ int sbase[8];
    if (threadIdx.x < 8) scnt[threadIdx.x] = 0;
    __syncthreads();
    const int base = blockIdx.x * 1024 + threadIdx.x * 4;
    const bool valid = base < e;           // e % 4 == 0
    int b_[4]; int r_[4]; uint32_t u_[4];
    if (valid) {
        vi4 d4 = __builtin_nontemporal_load((const vi4*)(dst + base));
        vi4 s4 = __builtin_nontemporal_load((const vi4*)(src + base));
        #pragma unroll
        for (int j = 0; j < 4; ++j) {
            int d = d4[j], s = s4[j];
            int b = d / RNODES;
            b_[j] = b;
            u_[j] = ((uint32_t)(d - b * RNODES) << 17) | (uint32_t)s;
            r_[j] = atomicAdd(&scnt[b], 1);   // LDS rank within block-bucket
        }
    }
    __syncthreads();
    if (threadIdx.x < 8)
        sbase[threadIdx.x] = atomicAdd(&bcnt[threadIdx.x], scnt[threadIdx.x]);
    __syncthreads();
    if (valid) {
        #pragma unroll
        for (int j = 0; j < 4; ++j) {
            int b = b_[j];
            bkt[(size_t)b * CAP + sbase[b] + r_[j]] = u_[j];
        }
    }
}

// ---------------- stage 2: per-XCD degree histogram from bucket ------------
__global__ __launch_bounds__(256) void k_hist2(const uint32_t* __restrict__ bkt,
                                               const int* __restrict__ bcnt,
                                               int* __restrict__ cnt) {
    const int xcd  = blockIdx.x & 7;
    const int blk  = blockIdx.x >> 3;
    const int nblk = (int)(gridDim.x >> 3);
    const int m = bcnt[xcd];
    const uint32_t* B = bkt + (size_t)xcd * CAP;
    const int lo = xcd * RNODES;
    for (int i = blk * 256 + threadIdx.x; i < m; i += nblk * 256)
        atomicAdd(&cnt[lo + (int)(B[i] >> 17)], 1);
}

// ---------------- exclusive scan (3 kernels) ----------------
__global__ __launch_bounds__(1024) void k_scan1(const int* __restrict__ cnt,
                                                int* __restrict__ excl,
                                                int* __restrict__ bsum, int n) {
    __shared__ int sh[1024];
    int i = blockIdx.x * 1024 + threadIdx.x;
    int v = (i < n) ? cnt[i] : 0;
    sh[threadIdx.x] = v;
    __syncthreads();
    for (int off = 1; off < 1024; off <<= 1) {
        int t = (threadIdx.x >= off) ? sh[threadIdx.x - off] : 0;
        __syncthreads();
        sh[threadIdx.x] += t;
        __syncthreads();
    }
    if (i < n) excl[i] = sh[threadIdx.x] - v;   // exclusive
    if (threadIdx.x == 1023) bsum[blockIdx.x] = sh[1023];
}

__global__ void k_scan2(int* __restrict__ bsum, int nb) {
    __shared__ int sh[128];
    int t = threadIdx.x;
    int v = (t < nb) ? bsum[t] : 0;
    sh[t] = v;
    __syncthreads();
    for (int off = 1; off < 128; off <<= 1) {
        int u = (t >= off) ? sh[t - off] : 0;
        __syncthreads();
        sh[t] += u;
        __syncthreads();
    }
    if (t < nb) bsum[t] = sh[t] - v;   // exclusive block offsets
}

// finalize row_ptr, init cursor, compute dis = rsqrt(deg+1)
__global__ void k_scan3(int* __restrict__ excl, const int* __restrict__ bsum,
                        int* __restrict__ cursor, const int* __restrict__ cnt,
                        float* __restrict__ dis, int n, int e) {
    int i = blockIdx.x * blockDim.x + threadIdx.x;
    if (i < n) {
        int v = excl[i] + bsum[i >> 10];
        excl[i] = v;
        cursor[i] = v;
        dis[i] = rsqrtf((float)(cnt[i] + 1));
    }
    if (i == 0) excl[n] = e;
}

// ---------------- stage 4: per-XCD CSR fill from bucket --------------------
// All cursor atomics + colw stores land in the home XCD's L2 slab; the only
// streaming read is the 800KB bucket -> no eviction thrash, 1x writeback.
__global__ __launch_bounds__(256) void k_fill2(const uint32_t* __restrict__ bkt,
                                               const int* __restrict__ bcnt,
                                               int* __restrict__ cursor,
                                               uint2* __restrict__ colw,
                                               const float* __restrict__ dis) {
    const int xcd  = blockIdx.x & 7;
    const int blk  = blockIdx.x >> 3;
    const int nblk = (int)(gridDim.x >> 3);
    const int m = bcnt[xcd];
    const uint32_t* B = bkt + (size_t)xcd * CAP;
    const int lo = xcd * RNODES;
    for (int i = blk * 256 + threadIdx.x; i < m; i += nblk * 256) {
        uint32_t u = B[i];
        int s = (int)(u & 0x1FFFFu);
        int d = lo + (int)(u >> 17);
        int pos = atomicAdd(&cursor[d], 1);
        uint2 cw;
        cw.x = (uint32_t)s;
        cw.y = __float_as_uint(dis[s] * dis[d]);
        colw[pos] = cw;
    }
}

// ---------------- GEMM: H[n x 128] = X[n x 128] @ W[128 x 128] -> bf16 -------
template <typename TIN>
__global__ __launch_bounds__(256) void k_gemm(const TIN* __restrict__ X,
                                              const float* __restrict__ W,
                                              unsigned short* __restrict__ H, int n) {
    __shared__ float At[64][68];   // [k][row]
    __shared__ float Ws[64][64];   // [k][col]
    const int t  = threadIdx.x;
    const int tx = t & 15;
    const int ty = t >> 4;
    const int rb = blockIdx.x * 64;
    const int cb = blockIdx.y * 64;

    float acc[4][4] = {};

    for (int c = 0; c < 2; ++c) {
        #pragma unroll
        for (int r = 0; r < 4; ++r) {
            int f   = t + 256 * r;        // 0..1023
            int row = f >> 4;             // 0..63
            int kc  = (f & 15) << 2;      // 0..60 step 4
            int grow = rb + row;
            float4 v = make_float4(0.f, 0.f, 0.f, 0.f);
            if (grow < n) {
                if constexpr (sizeof(TIN) == 4) {
                    v = *(const float4*)((const float*)X + (size_t)grow * FD + c * 64 + kc);
                } else {
                    uint2 p = *(const uint2*)((const unsigned short*)X + (size_t)grow * FD + c * 64 + kc);
                    v.x = bf_lo(p.x); v.y = bf_hi(p.x);
                    v.z = bf_lo(p.y); v.w = bf_hi(p.y);
                }
            }
            At[kc + 0][row] = v.x;
            At[kc + 1][row] = v.y;
            At[kc + 2][row] = v.z;
            At[kc + 3][row] = v.w;
            *(float4*)&Ws[row][kc] =
                *(const float4*)(W + (size_t)(c * 64 + row) * FD + cb + kc);
        }
        __syncthreads();
        #pragma unroll 8
        for (int k = 0; k < 64; ++k) {
            float4 a = *(const float4*)&At[k][ty * 4];
            float4 b = *(const float4*)&Ws[k][tx * 4];
            acc[0][0] = fmaf(a.x, b.x, acc[0][0]);
            acc[0][1] = fmaf(a.x, b.y, acc[0][1]);
            acc[0][2] = fmaf(a.x, b.z, acc[0][2]);
            acc[0][3] = fmaf(a.x, b.w, acc[0][3]);
            acc[1][0] = fmaf(a.y, b.x, acc[1][0]);
            acc[1][1] = fmaf(a.y, b.y, acc[1][1]);
            acc[1][2] = fmaf(a.y, b.z, acc[1][2]);
            acc[1][3] = fmaf(a.y, b.w, acc[1][3]);
            acc[2][0] = fmaf(a.z, b.x, acc[2][0]);
            acc[2][1] = fmaf(a.z, b.y, acc[2][1]);
            acc[2][2] = fmaf(a.z, b.z, acc[2][2]);
            acc[2][3] = fmaf(a.z, b.w, acc[2][3]);
            acc[3][0] = fmaf(a.w, b.x, acc[3][0]);
            acc[3][1] = fmaf(a.w, b.y, acc[3][1]);
            acc[3][2] = fmaf(a.w, b.z, acc[3][2]);
            acc[3][3] = fmaf(a.w, b.w, acc[3][3]);
        }
        __syncthreads();
    }

    #pragma unroll
    for (int i = 0; i < 4; ++i) {
        int grow = rb + ty * 4 + i;
        if (grow < n) {
            uint2 p;
            p.x = bf_pack(acc[i][0], acc[i][1]);
            p.y = bf_pack(acc[i][2], acc[i][3]);
            *(uint2*)(H + (size_t)grow * FD + cb + tx * 4) = p;
        }
    }
}

// ---------------- 128-wide aggregation over bf16 rows --------------------
// TWO nodes per wave; per node ceil(deg/16) 16-deep gather groups.
// MODE 0: writes relu rows (bf16). MODE 1: fused dot with W3 -> outf[i].
template <int MODE>
__global__ __launch_bounds__(256) void k_agg(const unsigned short* __restrict__ h,
                                             const float* __restrict__ dis,
                                             const int* __restrict__ rp,
                                             const uint2* __restrict__ colw,
                                             const float* __restrict__ bias,
                                             const float* __restrict__ W3,
                                             unsigned short* __restrict__ out,
                                             float* __restrict__ outf, int n) {
    const uint32_t* h32 = (const uint32_t*)h;   // 64 words per row
    int wid  = (int)((blockIdx.x * (size_t)blockDim.x + threadIdx.x) >> 6);
    int lane = threadIdx.x & 63;
    int w2 = __builtin_amdgcn_readfirstlane(wid);
    int i0 = 2 * w2;
    if (i0 >= n) return;
    int i1 = i0 + 1;
    const bool has1 = (i1 < n);

    const int e00 = rp[i0];
    const int e01 = rp[i0 + 1];
    const int e11 = has1 ? rp[i0 + 2] : e01;

    float di0 = dis[i0];
    float di1 = has1 ? dis[i1] : 0.f;
    float2 acc0, acc1;
    {
        uint32_t su0 = h32[(size_t)i0 * 64 + lane];
        float q0 = di0 * di0;
        acc0.x = bf_lo(su0) * q0; acc0.y = bf_hi(su0) * q0;
        if (has1) {
            uint32_t su1 = h32[(size_t)i1 * 64 + lane];
            float q1 = di1 * di1;
            acc1.x = bf_lo(su1) * q1; acc1.y = bf_hi(su1) * q1;
        } else { acc1.x = acc1.y = 0.f; }
    }

    const int ng0 = (e01 - e00 + 15) >> 4;
    const int ng1 = (e11 - e01 + 15) >> 4;
    const int ng  = ng0 > ng1 ? ng0 : ng1;

    for (int g = 0; g < ng; ++g) {
        const bool do0 = (g < ng0), do1 = (g < ng1);
        int s0[16], s1[16];
        float w0_[16], w1_[16];
        uint32_t v0[16], v1[16];
        if (do0) {
            const int jb = e00 + g * 16;
            if (jb + 16 <= e01) {
                #pragma unroll
                for (int q = 0; q < 16; ++q) {
                    uint2 cw = colw[jb + q];
                    s0[q] = (int)cw.x; w0_[q] = __uint_as_float(cw.y);
                }
            } else {
                #pragma unroll
                for (int q = 0; q < 16; ++q) {
                    int idx = jb + q;
                    int c   = idx < e01 ? idx : e01 - 1;
                    uint2 cw = colw[c];
                    s0[q]  = (int)cw.x;
                    w0_[q] = idx < e01 ? __uint_as_float(cw.y) : 0.f;
                }
            }
        }
        if (do1) {
            const int jb = e01 + g * 16;
            if (jb + 16 <= e11) {
                #pragma unroll
                for (int q = 0; q < 16; ++q) {
                    uint2 cw = colw[jb + q];
                    s1[q] = (int)cw.x; w1_[q] = __uint_as_float(cw.y);
                }
            } else {
                #pragma unroll
                for (int q = 0; q < 16; ++q) {
                    int idx = jb + q;
                    int c   = idx < e11 ? idx : e11 - 1;
                    uint2 cw = colw[c];
                    s1[q]  = (int)cw.x;
                    w1_[q] = idx < e11 ? __uint_as_float(cw.y) : 0.f;
                }
            }
        }
        if (do0) {
            #pragma unroll
            for (int q = 0; q < 16; ++q)
                v0[q] = h32[(size_t)s0[q] * 64 + lane];
        }
        if (do1) {
            #pragma unroll
            for (int q = 0; q < 16; ++q)
                v1[q] = h32[(size_t)s1[q] * 64 + lane];
        }
        if (do0) {
            #pragma unroll
            for (int q = 0; q < 16; ++q) {
                acc0.x = fmaf(w0_[q], bf_lo(v0[q]), acc0.x);
                acc0.y = fmaf(w0_[q], bf_hi(v0[q]), acc0.y);
            }
        }
        if (do1) {
            #pragma unroll
            for (int q = 0; q < 16; ++q) {
                acc1.x = fmaf(w1_[q], bf_lo(v1[q]), acc1.x);
                acc1.y = fmaf(w1_[q], bf_hi(v1[q]), acc1.y);
            }
        }
    }

    float2 b = ((const float2*)bias)[lane];
    acc0.x = fmaxf(acc0.x + b.x, 0.f);
    acc0.y = fmaxf(acc0.y + b.y, 0.f);
    acc1.x = fmaxf(acc1.x + b.x, 0.f);
    acc1.y = fmaxf(acc1.y + b.y, 0.f);

    if (MODE == 0) {
        ((uint32_t*)out)[(size_t)i0 * 64 + lane] = bf_pack(acc0.x, acc0.y);
        if (has1)
            ((uint32_t*)out)[(size_t)i1 * 64 + lane] = bf_pack(acc1.x, acc1.y);
    } else {
        float2 w3 = ((const float2*)W3)[lane];
        float d0 = acc0.x * w3.x + acc0.y * w3.y;
        float d1 = acc1.x * w3.x + acc1.y * w3.y;
        #pragma unroll
        for (int off = 32; off; off >>= 1) {
            d0 += __shfl_xor(d0, off);
            d1 += __shfl_xor(d1, off);
        }
        if (lane == 0) {
            outf[i0] = d0;
            if (has1) outf[i1] = d1;
        }
    }
}

// ---------------- scalar aggregation + bias + sigmoid (wave per node) ----------
__global__ __launch_bounds__(256) void k_agg1(const float* __restrict__ h3,
                                              const float* __restrict__ dis,
                                              const int* __restrict__ rp,
                                              const uint2* __restrict__ colw,
                                              const float* __restrict__ b3,
                                              float* __restrict__ out, int n) {
    int i    = (int)((blockIdx.x * (size_t)blockDim.x + threadIdx.x) >> 6);
    int lane = threadIdx.x & 63;
    if (i >= n) return;
    float di  = dis[i];
    float acc = (lane == 0) ? di * di * h3[i] : 0.f;
    const int e0 = rp[i], e1 = rp[i + 1];
    for (int base = e0 + lane; base < e1; base += 64) {
        uint2 cw = colw[base];
        acc = fmaf(__uint_as_float(cw.y), h3[(int)cw.x], acc);
    }
    #pragma unroll
    for (int off = 32; off; off >>= 1) acc += __shfl_xor(acc, off);
    if (lane == 0) {
        float v = acc + b3[0];
        out[i] = 1.f / (1.f + expf(-v));
    }
}

// ---------------- host launch ----------------
static inline size_t alg(size_t x) { return (x + 255) & ~(size_t)255; }

extern "C" void kernel_launch(void* const* d_in, const int* in_sizes, int n_in,
                              void* d_out, int out_size, void* d_ws, size_t ws_size,
                              hipStream_t stream) {
    const float* x   = (const float*)d_in[0];
    const int*   ei  = (const int*)d_in[1];     // [2, E]
    const float* W1  = (const float*)d_in[2];
    const float* b1  = (const float*)d_in[3];
    const float* W2  = (const float*)d_in[4];
    const float* b2  = (const float*)d_in[5];
    const float* W3  = (const float*)d_in[6];
    const float* b3  = (const float*)d_in[7];
    float*       out = (float*)d_out;

    const int n = NN, e = NE;
    const int* src = ei;
    const int* dst = ei + e;

    char* w = (char*)d_ws;
    float* dis    = (float*)w;  w += alg((size_t)n * 4);
    int*   cnt    = (int*)w;    w += alg((size_t)n * 4);
    int*   bcnt   = (int*)w;    w += alg((size_t)8 * 4);
    int*   rp     = (int*)w;    w += alg((size_t)(n + 1) * 4);
    int*   cursor = (int*)w;    w += alg((size_t)n * 4);
    int*   bsum   = (int*)w;    w += alg((size_t)128 * 4);
    uint32_t* bkt = (uint32_t*)w; w += alg((size_t)NXCD * CAP * 4);
    uint2* colw   = (uint2*)w;  w += alg((size_t)e * 8);
    unsigned short* bufA = (unsigned short*)w; w += alg((size_t)n * FD * 2);
    unsigned short* bufB = (unsigned short*)w; w += alg((size_t)n * FD * 2);
    float* h3     = (float*)w;  w += alg((size_t)n * 4);

    hipMemsetAsync(cnt, 0, (size_t)n * 4, stream);
    hipMemsetAsync(bcnt, 0, 8 * 4, stream);

    const int B = 256;
    const int gN = (n + B - 1) / B;
    const int nScan = (n + 1023) / 1024;   // 98
    const int nChunk = (e + 1023) / 1024;  // 1563

    k_part<<<nChunk, B, 0, stream>>>(src, dst, bkt, bcnt, e);
    k_hist2<<<2048, B, 0, stream>>>(bkt, bcnt, cnt);
    k_scan1<<<nScan, 1024, 0, stream>>>(cnt, rp, bsum, n);
    k_scan2<<<1, 128, 0, stream>>>(bsum, nScan);
    k_scan3<<<gN, B, 0, stream>>>(rp, bsum, cursor, cnt, dis, n, e);
    k_fill2<<<2048, B, 0, stream>>>(bkt, bcnt, cursor, colw, dis);

    dim3 gGemm((n + 63) / 64, 2);
    const int nWave2  = (n + 1) / 2;                    // two nodes per wave
    const int gWave2  = (nWave2 * 64 + B - 1) / B;      // blocks for k_agg
    const int gWave   = (n * 64 + B - 1) / B;           // wave per node (k_agg1)

    // layer 1
    k_gemm<float><<<gGemm, B, 0, stream>>>(x, W1, bufA, n);
    k_agg<0><<<gWave2, B, 0, stream>>>(bufA, dis, rp, colw, b1, W3, bufB, h3, n);
    // layer 2 (+ fused layer-3 matvec)
    k_gemm<unsigned short><<<gGemm, B, 0, stream>>>(bufB, W2, bufA, n);
    k_agg<1><<<gWave2, B, 0, stream>>>(bufA, dis, rp, colw, b2, W3, bufB, h3, n);
    // layer 3
    k_agg1<<<gWave, B, 0, stream>>>(h3, dis, rp, colw, b3, out, n);
}

// Round 10
// 486.387 us; speedup vs baseline: 1.0926x; 1.0796x over previous
//
#include <hip/hip_runtime.h>
#include <cstdint>
#include <cstddef>

#define NN 100000
#define NE 1600000
#define FD 128
#define NXCD 8
#define RNODES ((NN + NXCD - 1) / NXCD)   // 12500 nodes per XCD range
#define CAP 208192                        // per-bucket capacity (E/8 + 8k slack)

typedef int vi4 __attribute__((ext_vector_type(4)));
typedef __attribute__((ext_vector_type(8))) short bf16x8;
typedef __attribute__((ext_vector_type(4))) float f32x4;

// ---- bf16 helpers (RNE), storage-only precision reduction ----
__device__ __forceinline__ float bf_lo(uint32_t u) { return __uint_as_float(u << 16); }
__device__ __forceinline__ float bf_hi(uint32_t u) { return __uint_as_float(u & 0xffff0000u); }
__device__ __forceinline__ uint32_t bf_pack(float a, float b) {
    uint32_t ua = __float_as_uint(a), ub = __float_as_uint(b);
    ua += 0x7fffu + ((ua >> 16) & 1u);
    ub += 0x7fffu + ((ub >> 16) & 1u);
    return (ua >> 16) | (ub & 0xffff0000u);
}
__device__ __forceinline__ unsigned short bf1(float a) {
    uint32_t u = __float_as_uint(a);
    u += 0x7fffu + ((u >> 16) & 1u);
    return (unsigned short)(u >> 16);
}

// ---------------- stage 1: bucket partition (each edge read ONCE) ----------
// bkt[b] gets packed u = (dlo<<17) | s  (dlo<12500 fits 14b, s<100000 fits 17b)
__global__ __launch_bounds__(256) void k_part(const int* __restrict__ src,
                                              const int* __restrict__ dst,
                                              uint32_t* __restrict__ bkt,
                                              int* __restrict__ bcnt, int e) {
    __shared__ int scnt[8];
    __shared__ int sbase[8];
    if (threadIdx.x < 8) scnt[threadIdx.x] = 0;
    __syncthreads();
    const int base = blockIdx.x * 1024 + threadIdx.x * 4;
    const bool valid = base < e;           // e % 4 == 0
    int b_[4]; int r_[4]; uint32_t u_[4];
    if (valid) {
        vi4 d4 = __builtin_nontemporal_load((const vi4*)(dst + base));
        vi4 s4 = __builtin_nontemporal_load((const vi4*)(src + base));
        #pragma unroll
        for (int j = 0; j < 4; ++j) {
            int d = d4[j], s = s4[j];
            int b = d / RNODES;
            b_[j] = b;
            u_[j] = ((uint32_t)(d - b * RNODES) << 17) | (uint32_t)s;
            r_[j] = atomicAdd(&scnt[b], 1);   // LDS rank within block-bucket
        }
    }
    __syncthreads();
    if (threadIdx.x < 8)
        sbase[threadIdx.x] = atomicAdd(&bcnt[threadIdx.x], scnt[threadIdx.x]);
    __syncthreads();
    if (valid) {
        #pragma unroll
        for (int j = 0; j < 4; ++j) {
            int b = b_[j];
            bkt[(size_t)b * CAP + sbase[b] + r_[j]] = u_[j];
        }
    }
}

// ---------------- stage 2: per-XCD degree histogram from bucket ------------
__global__ __launch_bounds__(256) void k_hist2(const uint32_t* __restrict__ bkt,
                                               const int* __restrict__ bcnt,
                                               int* __restrict__ cnt) {
    const int xcd  = blockIdx.x & 7;
    const int blk  = blockIdx.x >> 3;
    const int nblk = (int)(gridDim.x >> 3);
    const int m = bcnt[xcd];
    const uint32_t* B = bkt + (size_t)xcd * CAP;
    const int lo = xcd * RNODES;
    for (int i = blk * 256 + threadIdx.x; i < m; i += nblk * 256)
        atomicAdd(&cnt[lo + (int)(B[i] >> 17)], 1);
}

// ---------------- exclusive scan (3 kernels) ----------------
__global__ __launch_bounds__(1024) void k_scan1(const int* __restrict__ cnt,
                                                int* __restrict__ excl,
                                                int* __restrict__ bsum, int n) {
    __shared__ int sh[1024];
    int i = blockIdx.x * 1024 + threadIdx.x;
    int v = (i < n) ? cnt[i] : 0;
    sh[threadIdx.x] = v;
    __syncthreads();
    for (int off = 1; off < 1024; off <<= 1) {
        int t = (threadIdx.x >= off) ? sh[threadIdx.x - off] : 0;
        __syncthreads();
        sh[threadIdx.x] += t;
        __syncthreads();
    }
    if (i < n) excl[i] = sh[threadIdx.x] - v;   // exclusive
    if (threadIdx.x == 1023) bsum[blockIdx.x] = sh[1023];
}

__global__ void k_scan2(int* __restrict__ bsum, int nb) {
    __shared__ int sh[128];
    int t = threadIdx.x;
    int v = (t < nb) ? bsum[t] : 0;
    sh[t] = v;
    __syncthreads();
    for (int off = 1; off < 128; off <<= 1) {
        int u = (t >= off) ? sh[t - off] : 0;
        __syncthreads();
        sh[t] += u;
        __syncthreads();
    }
    if (t < nb) bsum[t] = sh[t] - v;   // exclusive block offsets
}

// finalize row_ptr, init cursor, compute dis = rsqrt(deg+1)
__global__ void k_scan3(int* __restrict__ excl, const int* __restrict__ bsum,
                        int* __restrict__ cursor, const int* __restrict__ cnt,
                        float* __restrict__ dis, int n, int e) {
    int i = blockIdx.x * blockDim.x + threadIdx.x;
    if (i < n) {
        int v = excl[i] + bsum[i >> 10];
        excl[i] = v;
        cursor[i] = v;
        dis[i] = rsqrtf((float)(cnt[i] + 1));
    }
    if (i == 0) excl[n] = e;
}

// ---------------- stage 4: per-XCD CSR fill from bucket --------------------
__global__ __launch_bounds__(256) void k_fill2(const uint32_t* __restrict__ bkt,
                                               const int* __restrict__ bcnt,
                                               int* __restrict__ cursor,
                                               uint2* __restrict__ colw,
                                               const float* __restrict__ dis) {
    const int xcd  = blockIdx.x & 7;
    const int blk  = blockIdx.x >> 3;
    const int nblk = (int)(gridDim.x >> 3);
    const int m = bcnt[xcd];
    const uint32_t* B = bkt + (size_t)xcd * CAP;
    const int lo = xcd * RNODES;
    for (int i = blk * 256 + threadIdx.x; i < m; i += nblk * 256) {
        uint32_t u = B[i];
        int s = (int)(u & 0x1FFFFu);
        int d = lo + (int)(u >> 17);
        int pos = atomicAdd(&cursor[d], 1);
        uint2 cw;
        cw.x = (uint32_t)s;
        cw.y = __float_as_uint(dis[s] * dis[d]);
        colw[pos] = cw;
    }
}

// ---------------- MFMA GEMM: H[n x 128] = X[n x 128] @ W[128 x 128] -> bf16 --
// 256 thr = 4 waves; wave computes 16 rows x 128 cols via 16x16x32 bf16 MFMA.
// W staged transposed in LDS [n][k] bf16 (pad 136: 16B-aligned rows, 2-way
// bank conflict = free). A-frag: lane(row=l&15, k=(l>>4)*8..+7) contiguous 16B.
// C/D mapping (m89-verified): col=lane&15, row=(lane>>4)*4+j.
template <typename TIN>
__global__ __launch_bounds__(256) void k_gemm(const TIN* __restrict__ X,
                                              const float* __restrict__ W,
                                              unsigned short* __restrict__ H, int n) {
    __shared__ unsigned short Wl[128][136];   // [n][k] bf16
    const int t = threadIdx.x;
    #pragma unroll
    for (int c = 0; c < 16; ++c) {
        int idx4 = (c * 256 + t) * 4;        // 0..16380, within-row (4 | 128)
        int k  = idx4 >> 7;
        int nn = idx4 & 127;
        float4 v = *(const float4*)(W + idx4);
        Wl[nn + 0][k] = bf1(v.x);
        Wl[nn + 1][k] = bf1(v.y);
        Wl[nn + 2][k] = bf1(v.z);
        Wl[nn + 3][k] = bf1(v.w);
    }
    __syncthreads();

    const int wave = t >> 6, lane = t & 63;
    const int row0 = blockIdx.x * 64 + wave * 16;
    if (row0 >= n) return;                   // 16 | n, so strips are full
    const int arow = row0 + (lane & 15);
    const int kb8  = (lane >> 4) * 8;

    bf16x8 a[4];
    if constexpr (sizeof(TIN) == 4) {
        const float* Xf = (const float*)X;
        #pragma unroll
        for (int kt = 0; kt < 4; ++kt) {
            const float* p = Xf + (size_t)arow * FD + kt * 32 + kb8;
            float4 u0 = *(const float4*)p;
            float4 u1 = *(const float4*)(p + 4);
            bf16x8 f;
            f[0] = (short)bf1(u0.x); f[1] = (short)bf1(u0.y);
            f[2] = (short)bf1(u0.z); f[3] = (short)bf1(u0.w);
            f[4] = (short)bf1(u1.x); f[5] = (short)bf1(u1.y);
            f[6] = (short)bf1(u1.z); f[7] = (short)bf1(u1.w);
            a[kt] = f;
        }
    } else {
        const unsigned short* Xb = (const unsigned short*)X;
        #pragma unroll
        for (int kt = 0; kt < 4; ++kt)
            a[kt] = *(const bf16x8*)(Xb + (size_t)arow * FD + kt * 32 + kb8);
    }

    const int ccol  = lane & 15;
    const int crow0 = row0 + (lane >> 4) * 4;
    #pragma unroll
    for (int nt = 0; nt < 8; ++nt) {
        f32x4 acc = {0.f, 0.f, 0.f, 0.f};
        const int bcol = nt * 16 + (lane & 15);
        #pragma unroll
        for (int kt = 0; kt < 4; ++kt) {
            bf16x8 b = *(const bf16x8*)&Wl[bcol][kt * 32 + kb8];
            acc = __builtin_amdgcn_mfma_f32_16x16x32_bf16(a[kt], b, acc, 0, 0, 0);
        }
        #pragma unroll
        for (int j = 0; j < 4; ++j)
            H[(size_t)(crow0 + j) * FD + nt * 16 + ccol] = bf1(acc[j]);
    }
}

// ---------------- 128-wide aggregation over bf16 rows --------------------
// TWO nodes per wave; per node ceil(deg/16) 16-deep gather groups.
// MODE 0: writes relu rows (bf16). MODE 1: fused dot with W3 -> outf[i].
template <int MODE>
__global__ __launch_bounds__(256) void k_agg(const unsigned short* __restrict__ h,
                                             const float* __restrict__ dis,
                                             const int* __restrict__ rp,
                                             const uint2* __restrict__ colw,
                                             const float* __restrict__ bias,
                                             const float* __restrict__ W3,
                                             unsigned short* __restrict__ out,
                                             float* __restrict__ outf, int n) {
    const uint32_t* h32 = (const uint32_t*)h;   // 64 words per row
    int wid  = (int)((blockIdx.x * (size_t)blockDim.x + threadIdx.x) >> 6);
    int lane = threadIdx.x & 63;
    int w2 = __builtin_amdgcn_readfirstlane(wid);
    int i0 = 2 * w2;
    if (i0 >= n) return;
    int i1 = i0 + 1;
    const bool has1 = (i1 < n);

    const int e00 = rp[i0];
    const int e01 = rp[i0 + 1];
    const int e11 = has1 ? rp[i0 + 2] : e01;

    float di0 = dis[i0];
    float di1 = has1 ? dis[i1] : 0.f;
    float2 acc0, acc1;
    {
        uint32_t su0 = h32[(size_t)i0 * 64 + lane];
        float q0 = di0 * di0;
        acc0.x = bf_lo(su0) * q0; acc0.y = bf_hi(su0) * q0;
        if (has1) {
            uint32_t su1 = h32[(size_t)i1 * 64 + lane];
            float q1 = di1 * di1;
            acc1.x = bf_lo(su1) * q1; acc1.y = bf_hi(su1) * q1;
        } else { acc1.x = acc1.y = 0.f; }
    }

    const int ng0 = (e01 - e00 + 15) >> 4;
    const int ng1 = (e11 - e01 + 15) >> 4;
    const int ng  = ng0 > ng1 ? ng0 : ng1;

    for (int g = 0; g < ng; ++g) {
        const bool do0 = (g < ng0), do1 = (g < ng1);
        int s0[16], s1[16];
        float w0_[16], w1_[16];
        uint32_t v0[16], v1[16];
        if (do0) {
            const int jb = e00 + g * 16;
            if (jb + 16 <= e01) {
                #pragma unroll
                for (int q = 0; q < 16; ++q) {
                    uint2 cw = colw[jb + q];
                    s0[q] = (int)cw.x; w0_[q] = __uint_as_float(cw.y);
                }
            } else {
                #pragma unroll
                for (int q = 0; q < 16; ++q) {
                    int idx = jb + q;
                    int c   = idx < e01 ? idx : e01 - 1;
                    uint2 cw = colw[c];
                    s0[q]  = (int)cw.x;
                    w0_[q] = idx < e01 ? __uint_as_float(cw.y) : 0.f;
                }
            }
        }
        if (do1) {
            const int jb = e01 + g * 16;
            if (jb + 16 <= e11) {
                #pragma unroll
                for (int q = 0; q < 16; ++q) {
                    uint2 cw = colw[jb + q];
                    s1[q] = (int)cw.x; w1_[q] = __uint_as_float(cw.y);
                }
            } else {
                #pragma unroll
                for (int q = 0; q < 16; ++q) {
                    int idx = jb + q;
                    int c   = idx < e11 ? idx : e11 - 1;
                    uint2 cw = colw[c];
                    s1[q]  = (int)cw.x;
                    w1_[q] = idx < e11 ? __uint_as_float(cw.y) : 0.f;
                }
            }
        }
        if (do0) {
            #pragma unroll
            for (int q = 0; q < 16; ++q)
                v0[q] = h32[(size_t)s0[q] * 64 + lane];
        }
        if (do1) {
            #pragma unroll
            for (int q = 0; q < 16; ++q)
                v1[q] = h32[(size_t)s1[q] * 64 + lane];
        }
        if (do0) {
            #pragma unroll
            for (int q = 0; q < 16; ++q) {
                acc0.x = fmaf(w0_[q], bf_lo(v0[q]), acc0.x);
                acc0.y = fmaf(w0_[q], bf_hi(v0[q]), acc0.y);
            }
        }
        if (do1) {
            #pragma unroll
            for (int q = 0; q < 16; ++q) {
                acc1.x = fmaf(w1_[q], bf_lo(v1[q]), acc1.x);
                acc1.y = fmaf(w1_[q], bf_hi(v1[q]), acc1.y);
            }
        }
    }

    float2 b = ((const float2*)bias)[lane];
    acc0.x = fmaxf(acc0.x + b.x, 0.f);
    acc0.y = fmaxf(acc0.y + b.y, 0.f);
    acc1.x = fmaxf(acc1.x + b.x, 0.f);
    acc1.y = fmaxf(acc1.y + b.y, 0.f);

    if (MODE == 0) {
        ((uint32_t*)out)[(size_t)i0 * 64 + lane] = bf_pack(acc0.x, acc0.y);
        if (has1)
            ((uint32_t*)out)[(size_t)i1 * 64 + lane] = bf_pack(acc1.x, acc1.y);
    } else {
        float2 w3 = ((const float2*)W3)[lane];
        float d0 = acc0.x * w3.x + acc0.y * w3.y;
        float d1 = acc1.x * w3.x + acc1.y * w3.y;
        #pragma unroll
        for (int off = 32; off; off >>= 1) {
            d0 += __shfl_xor(d0, off);
            d1 += __shfl_xor(d1, off);
        }
        if (lane == 0) {
            outf[i0] = d0;
            if (has1) outf[i1] = d1;
        }
    }
}

// ---------------- scalar aggregation + bias + sigmoid (wave per node) ----------
__global__ __launch_bounds__(256) void k_agg1(const float* __restrict__ h3,
                                              const float* __restrict__ dis,
                                              const int* __restrict__ rp,
                                              const uint2* __restrict__ colw,
                                              const float* __restrict__ b3,
                                              float* __restrict__ out, int n) {
    int i    = (int)((blockIdx.x * (size_t)blockDim.x + threadIdx.x) >> 6);
    int lane = threadIdx.x & 63;
    if (i >= n) return;
    float di  = dis[i];
    float acc = (lane == 0) ? di * di * h3[i] : 0.f;
    const int e0 = rp[i], e1 = rp[i + 1];
    for (int base = e0 + lane; base < e1; base += 64) {
        uint2 cw = colw[base];
        acc = fmaf(__uint_as_float(cw.y), h3[(int)cw.x], acc);
    }
    #pragma unroll
    for (int off = 32; off; off >>= 1) acc += __shfl_xor(acc, off);
    if (lane == 0) {
        float v = acc + b3[0];
        out[i] = 1.f / (1.f + expf(-v));
    }
}

// ---------------- host launch ----------------
static inline size_t alg(size_t x) { return (x + 255) & ~(size_t)255; }

extern "C" void kernel_launch(void* const* d_in, const int* in_sizes, int n_in,
                              void* d_out, int out_size, void* d_ws, size_t ws_size,
                              hipStream_t stream) {
    const float* x   = (const float*)d_in[0];
    const int*   ei  = (const int*)d_in[1];     // [2, E]
    const float* W1  = (const float*)d_in[2];
    const float* b1  = (const float*)d_in[3];
    const float* W2  = (const float*)d_in[4];
    const float* b2  = (const float*)d_in[5];
    const float* W3  = (const float*)d_in[6];
    const float* b3  = (const float*)d_in[7];
    float*       out = (float*)d_out;

    const int n = NN, e = NE;
    const int* src = ei;
    const int* dst = ei + e;

    char* w = (char*)d_ws;
    float* dis    = (float*)w;  w += alg((size_t)n * 4);
    int*   cnt    = (int*)w;    w += alg((size_t)n * 4);
    int*   bcnt   = (int*)w;    w += alg((size_t)8 * 4);
    int*   rp     = (int*)w;    w += alg((size_t)(n + 1) * 4);
    int*   cursor = (int*)w;    w += alg((size_t)n * 4);
    int*   bsum   = (int*)w;    w += alg((size_t)128 * 4);
    uint32_t* bkt = (uint32_t*)w; w += alg((size_t)NXCD * CAP * 4);
    uint2* colw   = (uint2*)w;  w += alg((size_t)e * 8);
    unsigned short* bufA = (unsigned short*)w; w += alg((size_t)n * FD * 2);
    unsigned short* bufB = (unsigned short*)w; w += alg((size_t)n * FD * 2);
    float* h3     = (float*)w;  w += alg((size_t)n * 4);

    hipMemsetAsync(cnt, 0, (size_t)n * 4, stream);
    hipMemsetAsync(bcnt, 0, 8 * 4, stream);

    const int B = 256;
    const int gN = (n + B - 1) / B;
    const int nScan = (n + 1023) / 1024;   // 98
    const int nChunk = (e + 1023) / 1024;  // 1563

    k_part<<<nChunk, B, 0, stream>>>(src, dst, bkt, bcnt, e);
    k_hist2<<<2048, B, 0, stream>>>(bkt, bcnt, cnt);
    k_scan1<<<nScan, 1024, 0, stream>>>(cnt, rp, bsum, n);
    k_scan2<<<1, 128, 0, stream>>>(bsum, nScan);
    k_scan3<<<gN, B, 0, stream>>>(rp, bsum, cursor, cnt, dis, n, e);
    k_fill2<<<2048, B, 0, stream>>>(bkt, bcnt, cursor, colw, dis);

    const int gGemm = (n + 63) / 64;                    // 1563
    const int nWave2  = (n + 1) / 2;                    // two nodes per wave
    const int gWave2  = (nWave2 * 64 + B - 1) / B;      // blocks for k_agg
    const int gWave   = (n * 64 + B - 1) / B;           // wave per node (k_agg1)

    // layer 1
    k_gemm<float><<<gGemm, B, 0, stream>>>(x, W1, bufA, n);
    k_agg<0><<<gWave2, B, 0, stream>>>(bufA, dis, rp, colw, b1, W3, bufB, h3, n);
    // layer 2 (+ fused layer-3 matvec)
    k_gemm<unsigned short><<<gGemm, B, 0, stream>>>(bufB, W2, bufA, n);
    k_agg<1><<<gWave2, B, 0, stream>>>(bufA, dis, rp, colw, b2, W3, bufB, h3, n);
    // layer 3
    k_agg1<<<gWave, B, 0, stream>>>(h3, dis, rp, colw, b3, out, n);
}